// Round 9
// baseline (986.315 us; speedup 1.0000x reference)
//
#include <hip/hip_runtime.h>
#include <hip/hip_cooperative_groups.h>

namespace cg = cooperative_groups;

constexpr int N   = 100000;   // nodes
constexpr int E   = 1600000;  // message edges
constexpr int EP  = 200000;   // pos scored edges
constexpr int ES  = 400000;   // total scored edges (pos+neg)
constexpr int CAP = 64;       // per-node in-edge bucket capacity (Poisson(16): P(deg>=64)~1e-18)
constexpr int XG  = 8;        // XCD groups for dst-partitioned bucket fill
constexpr int DRANGE = (N + XG - 1) / XG;   // 12500 nodes per group
constexpr int NGEMM  = (N + 127) / 128;     // 782 gemm tiles
constexpr int NFILL  = XG * (E / 256);      // 50000 virtual fill blocks
constexpr int MAXG   = 1024;                // 4 blocks/CU x 256 CUs

typedef _Float16 f16x8 __attribute__((ext_vector_type(8)));
typedef _Float16 f16x4 __attribute__((ext_vector_type(4)));
typedef _Float16 f16x2 __attribute__((ext_vector_type(2)));
typedef float    f32x4 __attribute__((ext_vector_type(4)));

// ================================================================ mega kernel
// ALL phases grid-strided: correctness independent of nblk (round-8 bug:
// gemm assumed nblk >= 782; occupancy-derived nblk can be smaller -> poisoned
// H rows, absmax 0.058 ~= 0xAAAA-as-f16). __launch_bounds__(256,4).
__global__ __launch_bounds__(256, 4) void mega(
    const float* __restrict__ X,  const int* __restrict__ ei,
    const int* __restrict__ pe,   const int* __restrict__ ne,
    const float* __restrict__ W1, const float* __restrict__ b1,
    const float* __restrict__ W2, const float* __restrict__ b2,
    float* __restrict__ out, int* __restrict__ cnt, int* __restrict__ col,
    _Float16* __restrict__ H, float* __restrict__ Z, float* __restrict__ ZA,
    int nblk)
{
    cg::grid_group grid = cg::this_grid();
    __shared__ _Float16 As[128][40];   // gemm A tile [m][k], stride 40 f16 = 80 B
    __shared__ _Float16 Bs[128][40];   // gemm B tile [n][k] (W1 transposed)

    const int tid  = threadIdx.x;
    const int bid  = blockIdx.x;
    const int nthr = nblk << 8;
    const int gtid = (bid << 8) + tid;
    const int lane = tid & 63;

    // ---------------- P0: zero cnt (ws is poisoned 0xAA each call)
    for (int i = gtid; i < N; i += nthr) cnt[i] = 0;
    __threadfence();
    grid.sync();

    // ---------------- P1a: gemm1 (grid-strided over 782 tiles)
    for (int tb = bid; tb < NGEMM; tb += nblk) {
        const int wave = tid >> 6;
        const int m16  = lane & 15;
        const int quad = lane >> 4;
        const int blockRow = tb * 128;
        f32x4 acc[2][8] = {};
        for (int k0 = 0; k0 < 256; k0 += 32) {
            __syncthreads();   // previous tile's LDS reads complete
#pragma unroll
            for (int i = 0; i < 4; ++i) {
                int f  = tid + 256 * i;
                int r  = f >> 3;
                int kq = f & 7;
                int gr = blockRow + r;
                float4 v = (gr < N) ? *(const float4*)&X[(size_t)gr * 256 + k0 + kq * 4]
                                    : make_float4(0.f, 0.f, 0.f, 0.f);
                f16x4 h4;
                h4[0] = (_Float16)v.x; h4[1] = (_Float16)v.y;
                h4[2] = (_Float16)v.z; h4[3] = (_Float16)v.w;
                *(f16x4*)&As[r][kq * 4] = h4;
                int k  = f >> 5;
                int n4 = f & 31;
                float4 w = *(const float4*)&W1[(size_t)(k0 + k) * 128 + n4 * 4];
                Bs[n4 * 4 + 0][k] = (_Float16)w.x;
                Bs[n4 * 4 + 1][k] = (_Float16)w.y;
                Bs[n4 * 4 + 2][k] = (_Float16)w.z;
                Bs[n4 * 4 + 3][k] = (_Float16)w.w;
            }
            __syncthreads();
            f16x8 afrag[2];
#pragma unroll
            for (int mt = 0; mt < 2; ++mt)
                afrag[mt] = *(const f16x8*)&As[wave * 32 + mt * 16 + m16][quad * 8];
#pragma unroll
            for (int nt = 0; nt < 8; ++nt) {
                f16x8 bfrag = *(const f16x8*)&Bs[nt * 16 + m16][quad * 8];
                acc[0][nt] = __builtin_amdgcn_mfma_f32_16x16x32_f16(afrag[0], bfrag, acc[0][nt], 0, 0, 0);
                acc[1][nt] = __builtin_amdgcn_mfma_f32_16x16x32_f16(afrag[1], bfrag, acc[1][nt], 0, 0, 0);
            }
        }
        // epilogue: C/D layout col=lane&15, row=quad*4+r
#pragma unroll
        for (int mt = 0; mt < 2; ++mt)
#pragma unroll
            for (int nt = 0; nt < 8; ++nt)
#pragma unroll
                for (int r = 0; r < 4; ++r) {
                    int gm = blockRow + wave * 32 + mt * 16 + quad * 4 + r;
                    int gn = nt * 16 + m16;
                    if (gm < N) H[(size_t)gm * 128 + gn] = (_Float16)acc[mt][nt][r];
                }
    }
    // ---------------- P1b: bucket fill (grid-strided virtual blocks)
    // vb%8 constant per block (nblk%8==0) -> block stays in one dst partition
    // -> bucket-line writes merge within one XCD's L2.
    for (int vb = bid; vb < NFILL; vb += nblk) {
        const int g = vb & (XG - 1);
        const int e = (vb >> 3) * 256 + tid;
        const int d = ei[E + e];                // edge_index[1] = dst
        const unsigned rel = (unsigned)(d - g * DRANGE);
        if (rel < (unsigned)DRANGE) {
            const int s = ei[e];                // edge_index[0] = src
            const int p = atomicAdd(&cnt[d], 1);
            if (p < CAP) col[d * CAP + p] = s;
        }
    }
    __threadfence();
    grid.sync();

    // ---------------- P2: agg1 + gemm2 (wave per node, depth-4 prefetch)
    {
        const int wid0    = gtid >> 6;
        const int wstride = nthr >> 6;
        const _Float16* hbase = H + lane * 2;
        for (int n = wid0; n < N; n += wstride) {
            const int c = min(cnt[n], CAP);
            int sv = n;
            if (lane < c) sv = col[n * CAP + lane];
            const float dvw = rsqrtf((float)cnt[sv] + 1.0f);
            const float dv  = (lane <= c) ? dvw : 0.0f;
            const int ned4 = (c + 1 + 3) & ~3;

            f16x2 va[4]; float wa[4];
#pragma unroll
            for (int t = 0; t < 4; ++t) {
                const int   e = min(t, 63);
                const int   s = __shfl(sv, e);
                wa[t]         = __shfl(dv, e);
                va[t] = *(const f16x2*)&hbase[(size_t)s * 128];
            }
            float ax = 0.f, ay = 0.f;
            for (int j = 4; j < ned4; j += 4) {
                f16x2 vb[4]; float wb[4];
#pragma unroll
                for (int t = 0; t < 4; ++t) {
                    const int   e = min(j + t, 63);
                    const int   s = __shfl(sv, e);
                    wb[t]         = __shfl(dv, e);
                    vb[t] = *(const f16x2*)&hbase[(size_t)s * 128];
                }
#pragma unroll
                for (int t = 0; t < 4; ++t) {
                    ax = fmaf(wa[t], (float)va[t][0], ax);
                    ay = fmaf(wa[t], (float)va[t][1], ay);
                    va[t] = vb[t]; wa[t] = wb[t];
                }
            }
#pragma unroll
            for (int t = 0; t < 4; ++t) {
                ax = fmaf(wa[t], (float)va[t][0], ax);
                ay = fmaf(wa[t], (float)va[t][1], ay);
            }

            const float dn = __shfl(dv, c);     // dinv[n]
            const float2 b = *(const float2*)&b1[lane * 2];
            const float hr0 = fmaxf(ax * dn + b.x, 0.f);
            const float hr1 = fmaxf(ay * dn + b.y, 0.f);

            const float4 wa0 = *(const float4*)&W2[(size_t)(lane * 2) * 8];
            const float4 wa1 = *(const float4*)&W2[(size_t)(lane * 2) * 8 + 4];
            const float4 wb0 = *(const float4*)&W2[(size_t)(lane * 2 + 1) * 8];
            const float4 wb1 = *(const float4*)&W2[(size_t)(lane * 2 + 1) * 8 + 4];
            float p[8];
            p[0] = hr0 * wa0.x + hr1 * wb0.x;
            p[1] = hr0 * wa0.y + hr1 * wb0.y;
            p[2] = hr0 * wa0.z + hr1 * wb0.z;
            p[3] = hr0 * wa0.w + hr1 * wb0.w;
            p[4] = hr0 * wa1.x + hr1 * wb1.x;
            p[5] = hr0 * wa1.y + hr1 * wb1.y;
            p[6] = hr0 * wa1.z + hr1 * wb1.z;
            p[7] = hr0 * wa1.w + hr1 * wb1.w;
#pragma unroll
            for (int off = 32; off > 0; off >>= 1)
#pragma unroll
                for (int j = 0; j < 8; ++j) p[j] += __shfl_xor(p[j], off);
            if (lane == 0) {
                *(float4*)&Z[(size_t)n * 8]     = make_float4(p[0], p[1], p[2], p[3]);
                *(float4*)&Z[(size_t)n * 8 + 4] = make_float4(p[4], p[5], p[6], p[7]);
            }
        }
    }
    __threadfence();
    grid.sync();

    // ---------------- P3: agg2 (thread per node, depth-4 prefetch)
    for (int n = gtid; n < N; n += nthr) {
        const int c = min(cnt[n], CAP);
        float acc[8] = {};
        float4 va0[4], va1[4]; float wv[4];
#pragma unroll
        for (int t = 0; t < 4; ++t) {
            const int s = (t < c) ? col[n * CAP + t] : n;
            wv[t]  = (t < c) ? rsqrtf((float)cnt[s] + 1.0f) : 0.0f;
            va0[t] = *(const float4*)&Z[(size_t)s * 8];
            va1[t] = *(const float4*)&Z[(size_t)s * 8 + 4];
        }
        for (int j = 4; j + 4 <= c + 4; j += 4) {
            float4 vb0[4], vb1[4]; float wb[4];
#pragma unroll
            for (int t = 0; t < 4; ++t) {
                const int jt = j + t;
                const int s  = (jt < c) ? col[n * CAP + jt] : n;
                wb[t]  = (jt < c) ? rsqrtf((float)cnt[s] + 1.0f) : 0.0f;
                vb0[t] = *(const float4*)&Z[(size_t)s * 8];
                vb1[t] = *(const float4*)&Z[(size_t)s * 8 + 4];
            }
#pragma unroll
            for (int t = 0; t < 4; ++t) {
                const float w = wv[t];
                acc[0] = fmaf(w, va0[t].x, acc[0]); acc[1] = fmaf(w, va0[t].y, acc[1]);
                acc[2] = fmaf(w, va0[t].z, acc[2]); acc[3] = fmaf(w, va0[t].w, acc[3]);
                acc[4] = fmaf(w, va1[t].x, acc[4]); acc[5] = fmaf(w, va1[t].y, acc[5]);
                acc[6] = fmaf(w, va1[t].z, acc[6]); acc[7] = fmaf(w, va1[t].w, acc[7]);
                va0[t] = vb0[t]; va1[t] = vb1[t]; wv[t] = wb[t];
            }
        }
#pragma unroll
        for (int t = 0; t < 4; ++t) {
            const float w = wv[t];
            acc[0] = fmaf(w, va0[t].x, acc[0]); acc[1] = fmaf(w, va0[t].y, acc[1]);
            acc[2] = fmaf(w, va0[t].z, acc[2]); acc[3] = fmaf(w, va0[t].w, acc[3]);
            acc[4] = fmaf(w, va1[t].x, acc[4]); acc[5] = fmaf(w, va1[t].y, acc[5]);
            acc[6] = fmaf(w, va1[t].z, acc[6]); acc[7] = fmaf(w, va1[t].w, acc[7]);
        }
        const float dn = rsqrtf((float)c + 1.0f);
        const float4 zn0 = *(const float4*)&Z[(size_t)n * 8];
        const float4 zn1 = *(const float4*)&Z[(size_t)n * 8 + 4];
        float o[8];
        o[0] = (acc[0] + dn * zn0.x) * dn + b2[0];
        o[1] = (acc[1] + dn * zn0.y) * dn + b2[1];
        o[2] = (acc[2] + dn * zn0.z) * dn + b2[2];
        o[3] = (acc[3] + dn * zn0.w) * dn + b2[3];
        o[4] = (acc[4] + dn * zn1.x) * dn + b2[4];
        o[5] = (acc[5] + dn * zn1.y) * dn + b2[5];
        o[6] = (acc[6] + dn * zn1.z) * dn + b2[6];
        o[7] = (acc[7] + dn * zn1.w) * dn + b2[7];
        *(float4*)&ZA[(size_t)n * 8]     = make_float4(o[0], o[1], o[2], o[3]);
        *(float4*)&ZA[(size_t)n * 8 + 4] = make_float4(o[4], o[5], o[6], o[7]);
    }
    __threadfence();
    grid.sync();

    // ---------------- P4: edge scoring
    for (int e = gtid; e < ES; e += nthr) {
        int a, b;
        if (e < EP) { a = pe[e];      b = pe[EP + e]; }
        else        { a = ne[e - EP]; b = ne[e];      }
        const float4 xa0 = *(const float4*)&ZA[(size_t)a * 8];
        const float4 xa1 = *(const float4*)&ZA[(size_t)a * 8 + 4];
        const float4 xb0 = *(const float4*)&ZA[(size_t)b * 8];
        const float4 xb1 = *(const float4*)&ZA[(size_t)b * 8 + 4];
        out[e] = xa0.x * xb0.x + xa0.y * xb0.y + xa0.z * xb0.z + xa0.w * xb0.w +
                 xa1.x * xb1.x + xa1.y * xb1.y + xa1.z * xb1.z + xa1.w * xb1.w;
    }
}

// ================================================================ fallback
// Round-7 proven five-kernel path, used if cooperative launch fails.

__global__ __launch_bounds__(256) void fb_fill(const int* __restrict__ ei,
                                               int* __restrict__ cnt,
                                               int* __restrict__ col) {
    const int g     = blockIdx.x & (XG - 1);
    const int chunk = blockIdx.x >> 3;
    const int e     = chunk * 256 + threadIdx.x;
    const int d     = ei[E + e];
    const unsigned rel = (unsigned)(d - g * DRANGE);
    if (rel < (unsigned)DRANGE) {
        const int s = ei[e];
        const int p = atomicAdd(&cnt[d], 1);
        if (p < CAP) col[d * CAP + p] = s;
    }
}

__global__ __launch_bounds__(256) void fb_gemm1(const float* __restrict__ X,
                                                const float* __restrict__ W1,
                                                _Float16* __restrict__ H) {
    __shared__ _Float16 As[128][40];
    __shared__ _Float16 Bs[128][40];
    const int tid  = threadIdx.x;
    const int wave = tid >> 6;
    const int lane = tid & 63;
    const int m16  = lane & 15;
    const int quad = lane >> 4;
    const int blockRow = blockIdx.x * 128;
    f32x4 acc[2][8] = {};
    for (int k0 = 0; k0 < 256; k0 += 32) {
        __syncthreads();
#pragma unroll
        for (int i = 0; i < 4; ++i) {
            int f  = tid + 256 * i;
            int r  = f >> 3;
            int kq = f & 7;
            int gr = blockRow + r;
            float4 v = (gr < N) ? *(const float4*)&X[(size_t)gr * 256 + k0 + kq * 4]
                                : make_float4(0.f, 0.f, 0.f, 0.f);
            f16x4 h4;
            h4[0] = (_Float16)v.x; h4[1] = (_Float16)v.y;
            h4[2] = (_Float16)v.z; h4[3] = (_Float16)v.w;
            *(f16x4*)&As[r][kq * 4] = h4;
            int k  = f >> 5;
            int n4 = f & 31;
            float4 w = *(const float4*)&W1[(size_t)(k0 + k) * 128 + n4 * 4];
            Bs[n4 * 4 + 0][k] = (_Float16)w.x;
            Bs[n4 * 4 + 1][k] = (_Float16)w.y;
            Bs[n4 * 4 + 2][k] = (_Float16)w.z;
            Bs[n4 * 4 + 3][k] = (_Float16)w.w;
        }
        __syncthreads();
        f16x8 afrag[2];
#pragma unroll
        for (int mt = 0; mt < 2; ++mt)
            afrag[mt] = *(const f16x8*)&As[wave * 32 + mt * 16 + m16][quad * 8];
#pragma unroll
        for (int nt = 0; nt < 8; ++nt) {
            f16x8 bfrag = *(const f16x8*)&Bs[nt * 16 + m16][quad * 8];
            acc[0][nt] = __builtin_amdgcn_mfma_f32_16x16x32_f16(afrag[0], bfrag, acc[0][nt], 0, 0, 0);
            acc[1][nt] = __builtin_amdgcn_mfma_f32_16x16x32_f16(afrag[1], bfrag, acc[1][nt], 0, 0, 0);
        }
    }
#pragma unroll
    for (int mt = 0; mt < 2; ++mt)
#pragma unroll
        for (int nt = 0; nt < 8; ++nt)
#pragma unroll
            for (int r = 0; r < 4; ++r) {
                int gm = blockRow + wave * 32 + mt * 16 + quad * 4 + r;
                int gn = nt * 16 + m16;
                if (gm < N) H[(size_t)gm * 128 + gn] = (_Float16)acc[mt][nt][r];
            }
}

__global__ __launch_bounds__(256) void fb_agg1(const _Float16* __restrict__ H,
                                               const int* __restrict__ cnt,
                                               const int* __restrict__ col,
                                               const float* __restrict__ b1,
                                               const float* __restrict__ W2,
                                               float* __restrict__ Z) {
    const int n    = (blockIdx.x * blockDim.x + threadIdx.x) >> 6;
    const int lane = threadIdx.x & 63;
    if (n >= N) return;
    const int c = min(cnt[n], CAP);
    int sv = n;
    if (lane < c) sv = col[n * CAP + lane];
    const float dvw = rsqrtf((float)cnt[sv] + 1.0f);
    const float dv  = (lane <= c) ? dvw : 0.0f;
    const _Float16* hbase = H + lane * 2;
    const int ned4 = (c + 1 + 3) & ~3;
    f16x2 va[4]; float wa[4];
#pragma unroll
    for (int t = 0; t < 4; ++t) {
        const int   e = min(t, 63);
        const int   s = __shfl(sv, e);
        wa[t]         = __shfl(dv, e);
        va[t] = *(const f16x2*)&hbase[(size_t)s * 128];
    }
    float ax = 0.f, ay = 0.f;
    for (int j = 4; j < ned4; j += 4) {
        f16x2 vb[4]; float wb[4];
#pragma unroll
        for (int t = 0; t < 4; ++t) {
            const int   e = min(j + t, 63);
            const int   s = __shfl(sv, e);
            wb[t]         = __shfl(dv, e);
            vb[t] = *(const f16x2*)&hbase[(size_t)s * 128];
        }
#pragma unroll
        for (int t = 0; t < 4; ++t) {
            ax = fmaf(wa[t], (float)va[t][0], ax);
            ay = fmaf(wa[t], (float)va[t][1], ay);
            va[t] = vb[t]; wa[t] = wb[t];
        }
    }
#pragma unroll
    for (int t = 0; t < 4; ++t) {
        ax = fmaf(wa[t], (float)va[t][0], ax);
        ay = fmaf(wa[t], (float)va[t][1], ay);
    }
    const float dn = __shfl(dv, c);
    const float2 b = *(const float2*)&b1[lane * 2];
    const float hr0 = fmaxf(ax * dn + b.x, 0.f);
    const float hr1 = fmaxf(ay * dn + b.y, 0.f);
    const float4 wa0 = *(const float4*)&W2[(size_t)(lane * 2) * 8];
    const float4 wa1 = *(const float4*)&W2[(size_t)(lane * 2) * 8 + 4];
    const float4 wb0 = *(const float4*)&W2[(size_t)(lane * 2 + 1) * 8];
    const float4 wb1 = *(const float4*)&W2[(size_t)(lane * 2 + 1) * 8 + 4];
    float p[8];
    p[0] = hr0 * wa0.x + hr1 * wb0.x;
    p[1] = hr0 * wa0.y + hr1 * wb0.y;
    p[2] = hr0 * wa0.z + hr1 * wb0.z;
    p[3] = hr0 * wa0.w + hr1 * wb0.w;
    p[4] = hr0 * wa1.x + hr1 * wb1.x;
    p[5] = hr0 * wa1.y + hr1 * wb1.y;
    p[6] = hr0 * wa1.z + hr1 * wb1.z;
    p[7] = hr0 * wa1.w + hr1 * wb1.w;
#pragma unroll
    for (int off = 32; off > 0; off >>= 1)
#pragma unroll
        for (int j = 0; j < 8; ++j) p[j] += __shfl_xor(p[j], off);
    if (lane == 0) {
        *(float4*)&Z[(size_t)n * 8]     = make_float4(p[0], p[1], p[2], p[3]);
        *(float4*)&Z[(size_t)n * 8 + 4] = make_float4(p[4], p[5], p[6], p[7]);
    }
}

__global__ __launch_bounds__(256) void fb_agg2(const float* __restrict__ Z,
                                               const int* __restrict__ cnt,
                                               const int* __restrict__ col,
                                               const float* __restrict__ b2,
                                               float* __restrict__ ZA) {
    const int n = blockIdx.x * blockDim.x + threadIdx.x;
    if (n >= N) return;
    const int c = min(cnt[n], CAP);
    float acc[8] = {};
    for (int j = 0; j < c; ++j) {
        const int s = col[n * CAP + j];
        const float w = rsqrtf((float)cnt[s] + 1.0f);
        const float4 z0 = *(const float4*)&Z[(size_t)s * 8];
        const float4 z1 = *(const float4*)&Z[(size_t)s * 8 + 4];
        acc[0] = fmaf(w, z0.x, acc[0]); acc[1] = fmaf(w, z0.y, acc[1]);
        acc[2] = fmaf(w, z0.z, acc[2]); acc[3] = fmaf(w, z0.w, acc[3]);
        acc[4] = fmaf(w, z1.x, acc[4]); acc[5] = fmaf(w, z1.y, acc[5]);
        acc[6] = fmaf(w, z1.z, acc[6]); acc[7] = fmaf(w, z1.w, acc[7]);
    }
    const float dn = rsqrtf((float)c + 1.0f);
    const float4 zn0 = *(const float4*)&Z[(size_t)n * 8];
    const float4 zn1 = *(const float4*)&Z[(size_t)n * 8 + 4];
    float o[8];
    o[0] = (acc[0] + dn * zn0.x) * dn + b2[0];
    o[1] = (acc[1] + dn * zn0.y) * dn + b2[1];
    o[2] = (acc[2] + dn * zn0.z) * dn + b2[2];
    o[3] = (acc[3] + dn * zn0.w) * dn + b2[3];
    o[4] = (acc[4] + dn * zn1.x) * dn + b2[4];
    o[5] = (acc[5] + dn * zn1.y) * dn + b2[5];
    o[6] = (acc[6] + dn * zn1.z) * dn + b2[6];
    o[7] = (acc[7] + dn * zn1.w) * dn + b2[7];
    *(float4*)&ZA[(size_t)n * 8]     = make_float4(o[0], o[1], o[2], o[3]);
    *(float4*)&ZA[(size_t)n * 8 + 4] = make_float4(o[4], o[5], o[6], o[7]);
}

__global__ __launch_bounds__(256) void fb_score(const float* __restrict__ ZA,
                                                const int* __restrict__ pe,
                                                const int* __restrict__ ne,
                                                float* __restrict__ out) {
    const int e = blockIdx.x * blockDim.x + threadIdx.x;
    if (e >= ES) return;
    int a, b;
    if (e < EP) { a = pe[e];      b = pe[EP + e]; }
    else        { a = ne[e - EP]; b = ne[e];      }
    const float4 xa0 = *(const float4*)&ZA[(size_t)a * 8];
    const float4 xa1 = *(const float4*)&ZA[(size_t)a * 8 + 4];
    const float4 xb0 = *(const float4*)&ZA[(size_t)b * 8];
    const float4 xb1 = *(const float4*)&ZA[(size_t)b * 8 + 4];
    out[e] = xa0.x * xb0.x + xa0.y * xb0.y + xa0.z * xb0.z + xa0.w * xb0.w +
             xa1.x * xb1.x + xa1.y * xb1.y + xa1.z * xb1.z + xa1.w * xb1.w;
}

// ---------------------------------------------------------------- launch

extern "C" void kernel_launch(void* const* d_in, const int* in_sizes, int n_in,
                              void* d_out, int out_size, void* d_ws, size_t ws_size,
                              hipStream_t stream) {
    const float* x  = (const float*)d_in[0];
    const int*   ei = (const int*)d_in[1];   // [2, 1.6M] row-major
    const int*   pe = (const int*)d_in[2];   // [2, 200k]
    const int*   ne = (const int*)d_in[3];   // [2, 200k]
    const float* W1 = (const float*)d_in[4];
    const float* b1 = (const float*)d_in[5];
    const float* W2 = (const float*)d_in[6];
    const float* b2 = (const float*)d_in[7];
    float* out = (float*)d_out;

    char* ws = (char*)d_ws;
    size_t off = 0;
    auto carve = [&](size_t bytes) {
        char* p = ws + off;
        off += (bytes + 255) & ~(size_t)255;
        return p;
    };
    int*       cnt = (int*)      carve((size_t)N * sizeof(int));            // 0.4 MB
    int*       col = (int*)      carve((size_t)N * CAP * sizeof(int));      // 25.6 MB
    _Float16*  H   = (_Float16*) carve((size_t)N * 128 * sizeof(_Float16)); // 25.6 MB
    float*     Z   = (float*)    carve((size_t)N * 8 * sizeof(float));      // 3.2 MB
    float*     ZA  = (float*)    carve((size_t)N * 8 * sizeof(float));      // 3.2 MB

    // occupancy-derived grid (host-only queries; capture-safe; recomputed
    // every call -> identical work each call). Correctness never depends on
    // nblk: all mega phases are grid-strided.
    int maxb = 0;
    hipOccupancyMaxActiveBlocksPerMultiprocessor(&maxb, mega, 256, 0);
    int dev = 0, ncu = 0;
    hipGetDevice(&dev);
    hipDeviceGetAttribute(&ncu, hipDeviceAttributeMultiprocessorCount, dev);
    if (maxb < 1) maxb = 1;
    if (ncu  < 1) ncu  = 256;
    int nblk = maxb * ncu;
    if (nblk > MAXG) nblk = MAXG;
    nblk &= ~7;
    if (nblk < 8) nblk = 8;

    void* args[] = {
        (void*)&x, (void*)&ei, (void*)&pe, (void*)&ne, (void*)&W1, (void*)&b1,
        (void*)&W2, (void*)&b2, (void*)&out, (void*)&cnt, (void*)&col,
        (void*)&H, (void*)&Z, (void*)&ZA, (void*)&nblk
    };
    hipError_t err = hipLaunchCooperativeKernel(mega, dim3(nblk), dim3(256),
                                                args, 0, stream);
    if (err != hipSuccess) {
        // fallback: proven round-7 multi-kernel path (no grid.sync needed)
        hipMemsetAsync(cnt, 0, (size_t)N * sizeof(int), stream);
        fb_fill <<<XG * (E / 256), 256, 0, stream>>>(ei, cnt, col);
        fb_gemm1<<<NGEMM, 256, 0, stream>>>(x, W1, H);
        fb_agg1 <<<(N * 64 + 255) / 256, 256, 0, stream>>>(H, cnt, col, b1, W2, Z);
        fb_agg2 <<<(N + 255) / 256, 256, 0, stream>>>(Z, cnt, col, b2, ZA);
        fb_score<<<(ES + 255) / 256, 256, 0, stream>>>(ZA, pe, ne, out);
    }
}

// Round 10
// 436.524 us; speedup vs baseline: 2.2595x; 2.2595x over previous
//
#include <hip/hip_runtime.h>

constexpr int N   = 100000;   // nodes
constexpr int E   = 1600000;  // message edges
constexpr int EP  = 200000;   // pos scored edges
constexpr int ES  = 400000;   // total scored edges (pos+neg)
constexpr int CAP = 64;       // per-node in-edge bucket capacity (Poisson(16): P(deg>=64)~1e-18)
constexpr int XG  = 8;        // XCD groups for dst-partitioned bucket fill
constexpr int DRANGE = (N + XG - 1) / XG;   // 12500 nodes per group
constexpr int NH  = N / 2;    // agg1 half-range (profiling visibility split)

typedef _Float16 f16x8 __attribute__((ext_vector_type(8)));
typedef _Float16 f16x4 __attribute__((ext_vector_type(4)));
typedef _Float16 f16x2 __attribute__((ext_vector_type(2)));
typedef float    f32x4 __attribute__((ext_vector_type(4)));

// ---------------------------------------------------------------- bucket fill
// XCD-routed: blockIdx%8 round-robins XCDs (perf heuristic only); group g
// claims dst in [g*12500,(g+1)*12500) so each node's bucket line is written
// within one L2 -> ~16 writes merge, one writeback per line.
__global__ __launch_bounds__(256) void fill_buckets(const int* __restrict__ ei,
                                                    int* __restrict__ cnt,
                                                    int* __restrict__ col) {
    const int g     = blockIdx.x & (XG - 1);
    const int chunk = blockIdx.x >> 3;          // 0..6249
    const int e     = chunk * 256 + threadIdx.x;
    const int d     = ei[E + e];                // edge_index[1] = dst
    const unsigned rel = (unsigned)(d - g * DRANGE);
    if (rel < (unsigned)DRANGE) {
        const int s = ei[e];                    // edge_index[0] = src
        const int p = atomicAdd(&cnt[d], 1);
        if (p < CAP) col[d * CAP + p] = s;
    }
}

// ---------------------------------------------------------------- GEMM1 (f16 MFMA)
// H[100000,128](f16) = X @ W1 (f32->f16, fp32 accum), BM=128/BN=128/BK=32.
// Bs staging rework (round-9 evidence: 13.4M LDS conflict cycles from 16-way
// scalar transpose writes): thread gathers 8 k-consecutive W1 scalars for one
// n (L2-resident gather, 4 lines/instr) and stores ONE f16x8 -> wide LDS
// writes at disjoint bank ranges (intrinsic floor, no extra conflicts).
__global__ __launch_bounds__(256) void gemm1_mfma(const float* __restrict__ X,
                                                  const float* __restrict__ W1,
                                                  _Float16* __restrict__ H) {
    __shared__ _Float16 As[128][40];   // [m][k], stride 40 f16 = 80 B
    __shared__ _Float16 Bs[128][40];   // [n][k]  (W1 tile transposed)

    const int tid  = threadIdx.x;
    const int wave = tid >> 6;
    const int lane = tid & 63;
    const int m16  = lane & 15;
    const int quad = lane >> 4;
    const int blockRow = blockIdx.x * 128;

    f32x4 acc[2][8] = {};

    for (int k0 = 0; k0 < 256; k0 += 32) {
        __syncthreads();   // previous iteration's LDS reads complete
        // ---- stage A: 128 rows x 32 k, coalesced float4 reads, f16x4 writes
#pragma unroll
        for (int i = 0; i < 4; ++i) {
            int f  = tid + 256 * i;
            int r  = f >> 3;
            int kq = f & 7;
            int gr = blockRow + r;
            float4 v = (gr < N) ? *(const float4*)&X[(size_t)gr * 256 + k0 + kq * 4]
                                : make_float4(0.f, 0.f, 0.f, 0.f);
            f16x4 h4;
            h4[0] = (_Float16)v.x; h4[1] = (_Float16)v.y;
            h4[2] = (_Float16)v.z; h4[3] = (_Float16)v.w;
            *(f16x4*)&As[r][kq * 4] = h4;
        }
        // ---- stage B transposed: chunk c = [n (0..127)][kq (0..3)]; thread
        // gathers W1[k0+kq*8+i][n] i=0..7 and writes one f16x8 to Bs[n][kq*8].
#pragma unroll
        for (int i2 = 0; i2 < 2; ++i2) {
            int c  = tid + 256 * i2;
            int n  = c >> 2;
            int kq = c & 3;
            f16x8 h8;
#pragma unroll
            for (int i = 0; i < 8; ++i)
                h8[i] = (_Float16)W1[(size_t)(k0 + kq * 8 + i) * 128 + n];
            *(f16x8*)&Bs[n][kq * 8] = h8;
        }
        __syncthreads();
        // ---- compute on current LDS tile
        f16x8 afrag[2];
#pragma unroll
        for (int mt = 0; mt < 2; ++mt)
            afrag[mt] = *(const f16x8*)&As[wave * 32 + mt * 16 + m16][quad * 8];
#pragma unroll
        for (int nt = 0; nt < 8; ++nt) {
            f16x8 bfrag = *(const f16x8*)&Bs[nt * 16 + m16][quad * 8];
            acc[0][nt] = __builtin_amdgcn_mfma_f32_16x16x32_f16(afrag[0], bfrag, acc[0][nt], 0, 0, 0);
            acc[1][nt] = __builtin_amdgcn_mfma_f32_16x16x32_f16(afrag[1], bfrag, acc[1][nt], 0, 0, 0);
        }
    }
    // ---- epilogue: C/D layout col=lane&15, row=quad*4+r
#pragma unroll
    for (int mt = 0; mt < 2; ++mt)
#pragma unroll
        for (int nt = 0; nt < 8; ++nt)
#pragma unroll
            for (int r = 0; r < 4; ++r) {
                int gm = blockRow + wave * 32 + mt * 16 + quad * 4 + r;
                int gn = nt * 16 + m16;
                if (gm < N) H[(size_t)gm * 128 + gn] = (_Float16)acc[mt][nt][r];
            }
}

// ---------------------------------------------------------------- Fused agg1 + gemm2
// One wave per node; lane l owns feats [2l, 2l+1]; depth-4 double-buffered
// prefetch (proven best: 101 us full-range). Launched TWICE over half-ranges
// so the profiler's top-5 exposes the other kernels' true durations.
__global__ __launch_bounds__(256) void agg1_gemm2(const _Float16* __restrict__ H,
                                                  const int* __restrict__ cnt,
                                                  const int* __restrict__ col,
                                                  const float* __restrict__ b1,
                                                  const float* __restrict__ W2,
                                                  float* __restrict__ Z,
                                                  int nbase, int ncount) {
    const int nr   = (blockIdx.x * blockDim.x + threadIdx.x) >> 6;
    const int lane = threadIdx.x & 63;
    if (nr >= ncount) return;
    const int n = nbase + nr;
    const int c = min(cnt[n], CAP);

    int sv = n;
    if (lane < c) sv = col[n * CAP + lane];
    const float dvw = rsqrtf((float)cnt[sv] + 1.0f);
    const float dv  = (lane <= c) ? dvw : 0.0f;

    const _Float16* hbase = H + lane * 2;
    const int ned4 = (c + 1 + 3) & ~3;

    f16x2 va[4]; float wa[4];
#pragma unroll
    for (int t = 0; t < 4; ++t) {
        const int   e = min(t, 63);
        const int   s = __shfl(sv, e);
        wa[t]         = __shfl(dv, e);
        va[t] = *(const f16x2*)&hbase[(size_t)s * 128];
    }
    float ax = 0.f, ay = 0.f;
    for (int j = 4; j < ned4; j += 4) {
        f16x2 vb[4]; float wb[4];
#pragma unroll
        for (int t = 0; t < 4; ++t) {
            const int   e = min(j + t, 63);
            const int   s = __shfl(sv, e);
            wb[t]         = __shfl(dv, e);
            vb[t] = *(const f16x2*)&hbase[(size_t)s * 128];
        }
#pragma unroll
        for (int t = 0; t < 4; ++t) {
            ax = fmaf(wa[t], (float)va[t][0], ax);
            ay = fmaf(wa[t], (float)va[t][1], ay);
            va[t] = vb[t]; wa[t] = wb[t];
        }
    }
#pragma unroll
    for (int t = 0; t < 4; ++t) {
        ax = fmaf(wa[t], (float)va[t][0], ax);
        ay = fmaf(wa[t], (float)va[t][1], ay);
    }

    const float dn = __shfl(dv, c);         // dinv[n]
    const float2 b = *(const float2*)&b1[lane * 2];
    const float hr0 = fmaxf(ax * dn + b.x, 0.f);
    const float hr1 = fmaxf(ay * dn + b.y, 0.f);

    const float4 wa0 = *(const float4*)&W2[(size_t)(lane * 2) * 8];
    const float4 wa1 = *(const float4*)&W2[(size_t)(lane * 2) * 8 + 4];
    const float4 wb0 = *(const float4*)&W2[(size_t)(lane * 2 + 1) * 8];
    const float4 wb1 = *(const float4*)&W2[(size_t)(lane * 2 + 1) * 8 + 4];
    float p[8];
    p[0] = hr0 * wa0.x + hr1 * wb0.x;
    p[1] = hr0 * wa0.y + hr1 * wb0.y;
    p[2] = hr0 * wa0.z + hr1 * wb0.z;
    p[3] = hr0 * wa0.w + hr1 * wb0.w;
    p[4] = hr0 * wa1.x + hr1 * wb1.x;
    p[5] = hr0 * wa1.y + hr1 * wb1.y;
    p[6] = hr0 * wa1.z + hr1 * wb1.z;
    p[7] = hr0 * wa1.w + hr1 * wb1.w;
#pragma unroll
    for (int off = 32; off > 0; off >>= 1)
#pragma unroll
        for (int j = 0; j < 8; ++j) p[j] += __shfl_xor(p[j], off);
    if (lane == 0) {
        *(float4*)&Z[(size_t)n * 8]     = make_float4(p[0], p[1], p[2], p[3]);
        *(float4*)&Z[(size_t)n * 8 + 4] = make_float4(p[4], p[5], p[6], p[7]);
    }
}

// ---------------------------------------------------------------- Aggregation layer 2 (F=8)
// Thread per node, depth-4 prefetch; 64-thread blocks (1563 blocks) for finer
// CU load-balance than 391 blocks of 256.
__global__ __launch_bounds__(64) void agg2(const float* __restrict__ Z,
                                           const int* __restrict__ cnt,
                                           const int* __restrict__ col,
                                           const float* __restrict__ b2,
                                           float* __restrict__ ZA) {
    const int n = blockIdx.x * blockDim.x + threadIdx.x;
    if (n >= N) return;
    const int c = min(cnt[n], CAP);
    float acc[8] = {};

    float4 va0[4], va1[4]; float wv[4];
#pragma unroll
    for (int t = 0; t < 4; ++t) {
        const int s = (t < c) ? col[n * CAP + t] : n;
        wv[t]  = (t < c) ? rsqrtf((float)cnt[s] + 1.0f) : 0.0f;
        va0[t] = *(const float4*)&Z[(size_t)s * 8];
        va1[t] = *(const float4*)&Z[(size_t)s * 8 + 4];
    }
    for (int j = 4; j + 4 <= c + 4; j += 4) {
        float4 vb0[4], vb1[4]; float wb[4];
#pragma unroll
        for (int t = 0; t < 4; ++t) {
            const int jt = j + t;
            const int s  = (jt < c) ? col[n * CAP + jt] : n;
            wb[t]  = (jt < c) ? rsqrtf((float)cnt[s] + 1.0f) : 0.0f;
            vb0[t] = *(const float4*)&Z[(size_t)s * 8];
            vb1[t] = *(const float4*)&Z[(size_t)s * 8 + 4];
        }
#pragma unroll
        for (int t = 0; t < 4; ++t) {
            const float w = wv[t];
            acc[0] = fmaf(w, va0[t].x, acc[0]); acc[1] = fmaf(w, va0[t].y, acc[1]);
            acc[2] = fmaf(w, va0[t].z, acc[2]); acc[3] = fmaf(w, va0[t].w, acc[3]);
            acc[4] = fmaf(w, va1[t].x, acc[4]); acc[5] = fmaf(w, va1[t].y, acc[5]);
            acc[6] = fmaf(w, va1[t].z, acc[6]); acc[7] = fmaf(w, va1[t].w, acc[7]);
            va0[t] = vb0[t]; va1[t] = vb1[t]; wv[t] = wb[t];
        }
    }
#pragma unroll
    for (int t = 0; t < 4; ++t) {
        const float w = wv[t];
        acc[0] = fmaf(w, va0[t].x, acc[0]); acc[1] = fmaf(w, va0[t].y, acc[1]);
        acc[2] = fmaf(w, va0[t].z, acc[2]); acc[3] = fmaf(w, va0[t].w, acc[3]);
        acc[4] = fmaf(w, va1[t].x, acc[4]); acc[5] = fmaf(w, va1[t].y, acc[5]);
        acc[6] = fmaf(w, va1[t].z, acc[6]); acc[7] = fmaf(w, va1[t].w, acc[7]);
    }

    const float dn = rsqrtf((float)c + 1.0f);
    const float4 zn0 = *(const float4*)&Z[(size_t)n * 8];
    const float4 zn1 = *(const float4*)&Z[(size_t)n * 8 + 4];
    float o[8];
    o[0] = (acc[0] + dn * zn0.x) * dn + b2[0];
    o[1] = (acc[1] + dn * zn0.y) * dn + b2[1];
    o[2] = (acc[2] + dn * zn0.z) * dn + b2[2];
    o[3] = (acc[3] + dn * zn0.w) * dn + b2[3];
    o[4] = (acc[4] + dn * zn1.x) * dn + b2[4];
    o[5] = (acc[5] + dn * zn1.y) * dn + b2[5];
    o[6] = (acc[6] + dn * zn1.z) * dn + b2[6];
    o[7] = (acc[7] + dn * zn1.w) * dn + b2[7];
    *(float4*)&ZA[(size_t)n * 8]     = make_float4(o[0], o[1], o[2], o[3]);
    *(float4*)&ZA[(size_t)n * 8 + 4] = make_float4(o[4], o[5], o[6], o[7]);
}

// ---------------------------------------------------------------- Edge scoring
__global__ __launch_bounds__(256) void score(const float* __restrict__ ZA,
                                             const int* __restrict__ pe,
                                             const int* __restrict__ ne,
                                             float* __restrict__ out) {
    const int e = blockIdx.x * blockDim.x + threadIdx.x;
    if (e >= ES) return;
    int a, b;
    if (e < EP) { a = pe[e];      b = pe[EP + e]; }
    else        { a = ne[e - EP]; b = ne[e];      }
    const float4 xa0 = *(const float4*)&ZA[(size_t)a * 8];
    const float4 xa1 = *(const float4*)&ZA[(size_t)a * 8 + 4];
    const float4 xb0 = *(const float4*)&ZA[(size_t)b * 8];
    const float4 xb1 = *(const float4*)&ZA[(size_t)b * 8 + 4];
    out[e] = xa0.x * xb0.x + xa0.y * xb0.y + xa0.z * xb0.z + xa0.w * xb0.w +
             xa1.x * xb1.x + xa1.y * xb1.y + xa1.z * xb1.z + xa1.w * xb1.w;
}

// ---------------------------------------------------------------- launch

extern "C" void kernel_launch(void* const* d_in, const int* in_sizes, int n_in,
                              void* d_out, int out_size, void* d_ws, size_t ws_size,
                              hipStream_t stream) {
    const float* x  = (const float*)d_in[0];
    const int*   ei = (const int*)d_in[1];   // [2, 1.6M] row-major
    const int*   pe = (const int*)d_in[2];   // [2, 200k]
    const int*   ne = (const int*)d_in[3];   // [2, 200k]
    const float* W1 = (const float*)d_in[4];
    const float* b1 = (const float*)d_in[5];
    const float* W2 = (const float*)d_in[6];
    const float* b2 = (const float*)d_in[7];
    float* out = (float*)d_out;

    char* ws = (char*)d_ws;
    size_t off = 0;
    auto carve = [&](size_t bytes) {
        char* p = ws + off;
        off += (bytes + 255) & ~(size_t)255;
        return p;
    };
    int*       cnt = (int*)      carve((size_t)N * sizeof(int));            // 0.4 MB
    int*       col = (int*)      carve((size_t)N * CAP * sizeof(int));      // 25.6 MB
    _Float16*  H   = (_Float16*) carve((size_t)N * 128 * sizeof(_Float16)); // 25.6 MB
    float*     Z   = (float*)    carve((size_t)N * 8 * sizeof(float));      // 3.2 MB
    float*     ZA  = (float*)    carve((size_t)N * 8 * sizeof(float));      // 3.2 MB

    hipMemsetAsync(cnt, 0, (size_t)N * sizeof(int), stream);
    fill_buckets<<<XG * (E / 256), 256, 0, stream>>>(ei, cnt, col);
    gemm1_mfma  <<<(N + 127) / 128, 256, 0, stream>>>(x, W1, H);
    agg1_gemm2  <<<(NH * 64 + 255) / 256, 256, 0, stream>>>(H, cnt, col, b1, W2, Z, 0, NH);
    agg1_gemm2  <<<((N - NH) * 64 + 255) / 256, 256, 0, stream>>>(H, cnt, col, b1, W2, Z, NH, N - NH);
    agg2        <<<(N + 63) / 64, 64, 0, stream>>>(Z, cnt, col, b2, ZA);
    score       <<<(ES + 255) / 256, 256, 0, stream>>>(ZA, pe, ne, out);
}

// Round 11
// 427.314 us; speedup vs baseline: 2.3082x; 1.0216x over previous
//
#include <hip/hip_runtime.h>

constexpr int N   = 100000;   // nodes
constexpr int E   = 1600000;  // message edges
constexpr int EP  = 200000;   // pos scored edges
constexpr int ES  = 400000;   // total scored edges (pos+neg)
constexpr int CAP = 64;       // per-node in-edge bucket capacity (Poisson(16): P(deg>=64)~1e-18)
constexpr int XG  = 8;        // XCD groups for dst-partitioned bucket fill
constexpr int DRANGE = (N + XG - 1) / XG;   // 12500 nodes per group
constexpr int NH  = N / 2;    // agg1 half-range (profiling visibility split)

typedef _Float16 f16x8 __attribute__((ext_vector_type(8)));
typedef _Float16 f16x4 __attribute__((ext_vector_type(4)));
typedef _Float16 f16x2 __attribute__((ext_vector_type(2)));
typedef float    f32x4 __attribute__((ext_vector_type(4)));

// ---------------------------------------------------------------- bucket fill
// XCD-routed dst partition (blockIdx%8 -> XCD round-robin heuristic).
// Round-10 evidence: WRITE_SIZE 79 MB -> bucket-line merge mostly failing.
// Theory: the streamed ei reads (~6.4 MB/XCD) thrash the 4 MB L2, evicting
// bucket lines between the ~16 writes that should merge. Fix: NON-TEMPORAL
// loads for ei (no L2 allocation); col stores stay cached so they merge.
__global__ __launch_bounds__(256) void fill_buckets(const int* __restrict__ ei,
                                                    int* __restrict__ cnt,
                                                    int* __restrict__ col) {
    const int g     = blockIdx.x & (XG - 1);
    const int chunk = blockIdx.x >> 3;          // 0..6249
    const int e     = chunk * 256 + threadIdx.x;
    const int d     = __builtin_nontemporal_load(&ei[E + e]);   // dst
    const unsigned rel = (unsigned)(d - g * DRANGE);
    if (rel < (unsigned)DRANGE) {
        const int s = __builtin_nontemporal_load(&ei[e]);       // src
        const int p = atomicAdd(&cnt[d], 1);
        if (p < CAP) col[d * CAP + p] = s;
    }
}

// ---------------------------------------------------------------- GEMM1 (f16 MFMA)
// H[100000,128](f16) = X @ W1 (f32->f16, fp32 accum), BM=128/BN=128/BK=32.
// Bs staging: thread gathers 8 k-consecutive W1 scalars for one n and stores
// ONE f16x8 (round-10 rework removed the 16-way LDS conflicts).
__global__ __launch_bounds__(256) void gemm1_mfma(const float* __restrict__ X,
                                                  const float* __restrict__ W1,
                                                  _Float16* __restrict__ H) {
    __shared__ _Float16 As[128][40];   // [m][k], stride 40 f16 = 80 B
    __shared__ _Float16 Bs[128][40];   // [n][k]  (W1 tile transposed)

    const int tid  = threadIdx.x;
    const int wave = tid >> 6;
    const int lane = tid & 63;
    const int m16  = lane & 15;
    const int quad = lane >> 4;
    const int blockRow = blockIdx.x * 128;

    f32x4 acc[2][8] = {};

    for (int k0 = 0; k0 < 256; k0 += 32) {
        __syncthreads();   // previous iteration's LDS reads complete
#pragma unroll
        for (int i = 0; i < 4; ++i) {
            int f  = tid + 256 * i;
            int r  = f >> 3;
            int kq = f & 7;
            int gr = blockRow + r;
            float4 v = (gr < N) ? *(const float4*)&X[(size_t)gr * 256 + k0 + kq * 4]
                                : make_float4(0.f, 0.f, 0.f, 0.f);
            f16x4 h4;
            h4[0] = (_Float16)v.x; h4[1] = (_Float16)v.y;
            h4[2] = (_Float16)v.z; h4[3] = (_Float16)v.w;
            *(f16x4*)&As[r][kq * 4] = h4;
        }
#pragma unroll
        for (int i2 = 0; i2 < 2; ++i2) {
            int c  = tid + 256 * i2;
            int n  = c >> 2;
            int kq = c & 3;
            f16x8 h8;
#pragma unroll
            for (int i = 0; i < 8; ++i)
                h8[i] = (_Float16)W1[(size_t)(k0 + kq * 8 + i) * 128 + n];
            *(f16x8*)&Bs[n][kq * 8] = h8;
        }
        __syncthreads();
        f16x8 afrag[2];
#pragma unroll
        for (int mt = 0; mt < 2; ++mt)
            afrag[mt] = *(const f16x8*)&As[wave * 32 + mt * 16 + m16][quad * 8];
#pragma unroll
        for (int nt = 0; nt < 8; ++nt) {
            f16x8 bfrag = *(const f16x8*)&Bs[nt * 16 + m16][quad * 8];
            acc[0][nt] = __builtin_amdgcn_mfma_f32_16x16x32_f16(afrag[0], bfrag, acc[0][nt], 0, 0, 0);
            acc[1][nt] = __builtin_amdgcn_mfma_f32_16x16x32_f16(afrag[1], bfrag, acc[1][nt], 0, 0, 0);
        }
    }
#pragma unroll
    for (int mt = 0; mt < 2; ++mt)
#pragma unroll
        for (int nt = 0; nt < 8; ++nt)
#pragma unroll
            for (int r = 0; r < 4; ++r) {
                int gm = blockRow + wave * 32 + mt * 16 + quad * 4 + r;
                int gn = nt * 16 + m16;
                if (gm < N) H[(size_t)gm * 128 + gn] = (_Float16)acc[mt][nt][r];
            }
}

// ---------------------------------------------------------------- Fused agg1 + gemm2
// One wave per node; lane l owns feats [2l, 2l+1]; depth-4 double-buffered
// prefetch (proven best). Two half-range launches for profiler visibility.
__global__ __launch_bounds__(256) void agg1_gemm2(const _Float16* __restrict__ H,
                                                  const int* __restrict__ cnt,
                                                  const int* __restrict__ col,
                                                  const float* __restrict__ b1,
                                                  const float* __restrict__ W2,
                                                  float* __restrict__ Z,
                                                  int nbase, int ncount) {
    const int nr   = (blockIdx.x * blockDim.x + threadIdx.x) >> 6;
    const int lane = threadIdx.x & 63;
    if (nr >= ncount) return;
    const int n = nbase + nr;
    const int c = min(cnt[n], CAP);

    int sv = n;
    if (lane < c) sv = col[n * CAP + lane];
    const float dvw = rsqrtf((float)cnt[sv] + 1.0f);
    const float dv  = (lane <= c) ? dvw : 0.0f;

    const _Float16* hbase = H + lane * 2;
    const int ned4 = (c + 1 + 3) & ~3;

    f16x2 va[4]; float wa[4];
#pragma unroll
    for (int t = 0; t < 4; ++t) {
        const int   e = min(t, 63);
        const int   s = __shfl(sv, e);
        wa[t]         = __shfl(dv, e);
        va[t] = *(const f16x2*)&hbase[(size_t)s * 128];
    }
    float ax = 0.f, ay = 0.f;
    for (int j = 4; j < ned4; j += 4) {
        f16x2 vb[4]; float wb[4];
#pragma unroll
        for (int t = 0; t < 4; ++t) {
            const int   e = min(j + t, 63);
            const int   s = __shfl(sv, e);
            wb[t]         = __shfl(dv, e);
            vb[t] = *(const f16x2*)&hbase[(size_t)s * 128];
        }
#pragma unroll
        for (int t = 0; t < 4; ++t) {
            ax = fmaf(wa[t], (float)va[t][0], ax);
            ay = fmaf(wa[t], (float)va[t][1], ay);
            va[t] = vb[t]; wa[t] = wb[t];
        }
    }
#pragma unroll
    for (int t = 0; t < 4; ++t) {
        ax = fmaf(wa[t], (float)va[t][0], ax);
        ay = fmaf(wa[t], (float)va[t][1], ay);
    }

    const float dn = __shfl(dv, c);         // dinv[n]
    const float2 b = *(const float2*)&b1[lane * 2];
    const float hr0 = fmaxf(ax * dn + b.x, 0.f);
    const float hr1 = fmaxf(ay * dn + b.y, 0.f);

    const float4 wa0 = *(const float4*)&W2[(size_t)(lane * 2) * 8];
    const float4 wa1 = *(const float4*)&W2[(size_t)(lane * 2) * 8 + 4];
    const float4 wb0 = *(const float4*)&W2[(size_t)(lane * 2 + 1) * 8];
    const float4 wb1 = *(const float4*)&W2[(size_t)(lane * 2 + 1) * 8 + 4];
    float p[8];
    p[0] = hr0 * wa0.x + hr1 * wb0.x;
    p[1] = hr0 * wa0.y + hr1 * wb0.y;
    p[2] = hr0 * wa0.z + hr1 * wb0.z;
    p[3] = hr0 * wa0.w + hr1 * wb0.w;
    p[4] = hr0 * wa1.x + hr1 * wb1.x;
    p[5] = hr0 * wa1.y + hr1 * wb1.y;
    p[6] = hr0 * wa1.z + hr1 * wb1.z;
    p[7] = hr0 * wa1.w + hr1 * wb1.w;
#pragma unroll
    for (int off = 32; off > 0; off >>= 1)
#pragma unroll
        for (int j = 0; j < 8; ++j) p[j] += __shfl_xor(p[j], off);
    if (lane == 0) {
        *(float4*)&Z[(size_t)n * 8]     = make_float4(p[0], p[1], p[2], p[3]);
        *(float4*)&Z[(size_t)n * 8 + 4] = make_float4(p[4], p[5], p[6], p[7]);
    }
}

// ---------------------------------------------------------------- Aggregation layer 2 (F=8)
// Thread per node, depth-4 prefetch; 64-thread blocks for CU load-balance.
__global__ __launch_bounds__(64) void agg2(const float* __restrict__ Z,
                                           const int* __restrict__ cnt,
                                           const int* __restrict__ col,
                                           const float* __restrict__ b2,
                                           float* __restrict__ ZA) {
    const int n = blockIdx.x * blockDim.x + threadIdx.x;
    if (n >= N) return;
    const int c = min(cnt[n], CAP);
    float acc[8] = {};

    float4 va0[4], va1[4]; float wv[4];
#pragma unroll
    for (int t = 0; t < 4; ++t) {
        const int s = (t < c) ? col[n * CAP + t] : n;
        wv[t]  = (t < c) ? rsqrtf((float)cnt[s] + 1.0f) : 0.0f;
        va0[t] = *(const float4*)&Z[(size_t)s * 8];
        va1[t] = *(const float4*)&Z[(size_t)s * 8 + 4];
    }
    for (int j = 4; j + 4 <= c + 4; j += 4) {
        float4 vb0[4], vb1[4]; float wb[4];
#pragma unroll
        for (int t = 0; t < 4; ++t) {
            const int jt = j + t;
            const int s  = (jt < c) ? col[n * CAP + jt] : n;
            wb[t]  = (jt < c) ? rsqrtf((float)cnt[s] + 1.0f) : 0.0f;
            vb0[t] = *(const float4*)&Z[(size_t)s * 8];
            vb1[t] = *(const float4*)&Z[(size_t)s * 8 + 4];
        }
#pragma unroll
        for (int t = 0; t < 4; ++t) {
            const float w = wv[t];
            acc[0] = fmaf(w, va0[t].x, acc[0]); acc[1] = fmaf(w, va0[t].y, acc[1]);
            acc[2] = fmaf(w, va0[t].z, acc[2]); acc[3] = fmaf(w, va0[t].w, acc[3]);
            acc[4] = fmaf(w, va1[t].x, acc[4]); acc[5] = fmaf(w, va1[t].y, acc[5]);
            acc[6] = fmaf(w, va1[t].z, acc[6]); acc[7] = fmaf(w, va1[t].w, acc[7]);
            va0[t] = vb0[t]; va1[t] = vb1[t]; wv[t] = wb[t];
        }
    }
#pragma unroll
    for (int t = 0; t < 4; ++t) {
        const float w = wv[t];
        acc[0] = fmaf(w, va0[t].x, acc[0]); acc[1] = fmaf(w, va0[t].y, acc[1]);
        acc[2] = fmaf(w, va0[t].z, acc[2]); acc[3] = fmaf(w, va0[t].w, acc[3]);
        acc[4] = fmaf(w, va1[t].x, acc[4]); acc[5] = fmaf(w, va1[t].y, acc[5]);
        acc[6] = fmaf(w, va1[t].z, acc[6]); acc[7] = fmaf(w, va1[t].w, acc[7]);
    }

    const float dn = rsqrtf((float)c + 1.0f);
    const float4 zn0 = *(const float4*)&Z[(size_t)n * 8];
    const float4 zn1 = *(const float4*)&Z[(size_t)n * 8 + 4];
    float o[8];
    o[0] = (acc[0] + dn * zn0.x) * dn + b2[0];
    o[1] = (acc[1] + dn * zn0.y) * dn + b2[1];
    o[2] = (acc[2] + dn * zn0.z) * dn + b2[2];
    o[3] = (acc[3] + dn * zn0.w) * dn + b2[3];
    o[4] = (acc[4] + dn * zn1.x) * dn + b2[4];
    o[5] = (acc[5] + dn * zn1.y) * dn + b2[5];
    o[6] = (acc[6] + dn * zn1.z) * dn + b2[6];
    o[7] = (acc[7] + dn * zn1.w) * dn + b2[7];
    *(float4*)&ZA[(size_t)n * 8]     = make_float4(o[0], o[1], o[2], o[3]);
    *(float4*)&ZA[(size_t)n * 8 + 4] = make_float4(o[4], o[5], o[6], o[7]);
}

// ---------------------------------------------------------------- Edge scoring
__global__ __launch_bounds__(256) void score(const float* __restrict__ ZA,
                                             const int* __restrict__ pe,
                                             const int* __restrict__ ne,
                                             float* __restrict__ out) {
    const int e = blockIdx.x * blockDim.x + threadIdx.x;
    if (e >= ES) return;
    int a, b;
    if (e < EP) { a = pe[e];      b = pe[EP + e]; }
    else        { a = ne[e - EP]; b = ne[e];      }
    const float4 xa0 = *(const float4*)&ZA[(size_t)a * 8];
    const float4 xa1 = *(const float4*)&ZA[(size_t)a * 8 + 4];
    const float4 xb0 = *(const float4*)&ZA[(size_t)b * 8];
    const float4 xb1 = *(const float4*)&ZA[(size_t)b * 8 + 4];
    out[e] = xa0.x * xb0.x + xa0.y * xb0.y + xa0.z * xb0.z + xa0.w * xb0.w +
             xa1.x * xb1.x + xa1.y * xb1.y + xa1.z * xb1.z + xa1.w * xb1.w;
}

// ---------------------------------------------------------------- launch

extern "C" void kernel_launch(void* const* d_in, const int* in_sizes, int n_in,
                              void* d_out, int out_size, void* d_ws, size_t ws_size,
                              hipStream_t stream) {
    const float* x  = (const float*)d_in[0];
    const int*   ei = (const int*)d_in[1];   // [2, 1.6M] row-major
    const int*   pe = (const int*)d_in[2];   // [2, 200k]
    const int*   ne = (const int*)d_in[3];   // [2, 200k]
    const float* W1 = (const float*)d_in[4];
    const float* b1 = (const float*)d_in[5];
    const float* W2 = (const float*)d_in[6];
    const float* b2 = (const float*)d_in[7];
    float* out = (float*)d_out;

    char* ws = (char*)d_ws;
    size_t off = 0;
    auto carve = [&](size_t bytes) {
        char* p = ws + off;
        off += (bytes + 255) & ~(size_t)255;
        return p;
    };
    int*       cnt = (int*)      carve((size_t)N * sizeof(int));            // 0.4 MB
    int*       col = (int*)      carve((size_t)N * CAP * sizeof(int));      // 25.6 MB
    _Float16*  H   = (_Float16*) carve((size_t)N * 128 * sizeof(_Float16)); // 25.6 MB
    float*     Z   = (float*)    carve((size_t)N * 8 * sizeof(float));      // 3.2 MB
    float*     ZA  = (float*)    carve((size_t)N * 8 * sizeof(float));      // 3.2 MB

    hipMemsetAsync(cnt, 0, (size_t)N * sizeof(int), stream);
    fill_buckets<<<XG * (E / 256), 256, 0, stream>>>(ei, cnt, col);
    gemm1_mfma  <<<(N + 127) / 128, 256, 0, stream>>>(x, W1, H);
    agg1_gemm2  <<<(NH * 64 + 255) / 256, 256, 0, stream>>>(H, cnt, col, b1, W2, Z, 0, NH);
    agg1_gemm2  <<<((N - NH) * 64 + 255) / 256, 256, 0, stream>>>(H, cnt, col, b1, W2, Z, NH, N - NH);
    agg2        <<<(N + 63) / 64, 64, 0, stream>>>(Z, cnt, col, b2, ZA);
    score       <<<(ES + 255) / 256, 256, 0, stream>>>(ZA, pe, ne, out);
}

// Round 12
// 417.661 us; speedup vs baseline: 2.3615x; 1.0231x over previous
//
#include <hip/hip_runtime.h>

constexpr int N   = 100000;   // nodes
constexpr int E   = 1600000;  // message edges
constexpr int EP  = 200000;   // pos scored edges
constexpr int ES  = 400000;   // total scored edges (pos+neg)
constexpr int CAP = 64;       // per-node in-edge bucket capacity (Poisson(16): P(deg>=64)~1e-18)
constexpr int XG  = 8;        // XCD groups for dst-partitioned bucket fill
constexpr int DRANGE = (N + XG - 1) / XG;   // 12500 nodes per group
constexpr int NH  = N / 2;    // agg1 half-range (profiling visibility split)

typedef _Float16 f16x8 __attribute__((ext_vector_type(8)));
typedef _Float16 f16x4 __attribute__((ext_vector_type(4)));
typedef _Float16 f16x2 __attribute__((ext_vector_type(2)));
typedef float    f32x4 __attribute__((ext_vector_type(4)));

// ---------------------------------------------------------------- bucket fill
// XCD-routed dst partition + NON-TEMPORAL ei loads (round-11: removed fill
// from top-5; streamed reads no longer thrash bucket lines out of L2).
__global__ __launch_bounds__(256) void fill_buckets(const int* __restrict__ ei,
                                                    int* __restrict__ cnt,
                                                    int* __restrict__ col) {
    const int g     = blockIdx.x & (XG - 1);
    const int chunk = blockIdx.x >> 3;          // 0..6249
    const int e     = chunk * 256 + threadIdx.x;
    const int d     = __builtin_nontemporal_load(&ei[E + e]);   // dst
    const unsigned rel = (unsigned)(d - g * DRANGE);
    if (rel < (unsigned)DRANGE) {
        const int s = __builtin_nontemporal_load(&ei[e]);       // src
        const int p = atomicAdd(&cnt[d], 1);
        if (p < CAP) col[d * CAP + p] = s;
    }
}

// ---------------------------------------------------------------- GEMM1 (f16 MFMA)
// H[100000,128](f16) = X @ W1 (f32->f16, fp32 accum).
// Round-12: BM 128->64 (1563 blocks, ~6/CU co-resident vs 3 — round-11
// counters showed 20% occupancy, MfmaUtil 3%, VALU 5%: latency-starved) and
// register-prefetch pipeline restored (next tile's A loads + B gather staged
// in regs before current tile's MFMA). B gather packs f16x8 at load time.
__global__ __launch_bounds__(256) void gemm1_mfma(const float* __restrict__ X,
                                                  const float* __restrict__ W1,
                                                  _Float16* __restrict__ H) {
    __shared__ _Float16 As[64][40];    // [m][k], stride 40 f16 = 80 B (16B-aligned rows)
    __shared__ _Float16 Bs[128][40];   // [n][k]  (W1 tile transposed)

    const int tid  = threadIdx.x;
    const int wave = tid >> 6;
    const int lane = tid & 63;
    const int m16  = lane & 15;
    const int quad = lane >> 4;
    const int blockRow = blockIdx.x * 64;

    f32x4 acc[8] = {};      // wave covers rows [wave*16, wave*16+16) x all 128 cols

    // A staging: 64 rows x 32 k = 512 float4 -> 2/thread
    const int aR  = tid >> 2;          // wait: 512 float4 over 256 threads = 2 each
    // chunk f = tid + 256*i : r = f>>3 (0..63), kq = f&7
    // B staging: chunks c = tid + 256*i2 : n = c>>2 (0..127), kq = c&3
    float4 avA[2];
    f16x8  bvB[2];
    (void)aR;

    auto loadA = [&](int k0) {
#pragma unroll
        for (int i = 0; i < 2; ++i) {
            int f  = tid + 256 * i;
            int r  = f >> 3;
            int kq = f & 7;
            int gr = blockRow + r;
            avA[i] = (gr < N) ? *(const float4*)&X[(size_t)gr * 256 + k0 + kq * 4]
                              : make_float4(0.f, 0.f, 0.f, 0.f);
        }
    };
    auto loadB = [&](int k0) {
#pragma unroll
        for (int i2 = 0; i2 < 2; ++i2) {
            int c  = tid + 256 * i2;
            int n  = c >> 2;
            int kq = c & 3;
            f16x8 h8;
#pragma unroll
            for (int i = 0; i < 8; ++i)
                h8[i] = (_Float16)W1[(size_t)(k0 + kq * 8 + i) * 128 + n];
            bvB[i2] = h8;
        }
    };

    loadA(0); loadB(0);
    for (int k0 = 0; k0 < 256; k0 += 32) {
        __syncthreads();   // previous iteration's LDS reads complete
        // ---- store staged registers
#pragma unroll
        for (int i = 0; i < 2; ++i) {
            int f  = tid + 256 * i;
            int r  = f >> 3;
            int kq = f & 7;
            f16x4 h4;
            h4[0] = (_Float16)avA[i].x; h4[1] = (_Float16)avA[i].y;
            h4[2] = (_Float16)avA[i].z; h4[3] = (_Float16)avA[i].w;
            *(f16x4*)&As[r][kq * 4] = h4;
            int c  = f;                 // same chunk index for B
            int n  = c >> 2;
            int bq = c & 3;
            *(f16x8*)&Bs[n][bq * 8] = bvB[i];
        }
        __syncthreads();
        // ---- issue next tile's global loads (hide under MFMA below)
        if (k0 + 32 < 256) { loadA(k0 + 32); loadB(k0 + 32); }
        // ---- compute on current LDS tile
        f16x8 afrag = *(const f16x8*)&As[wave * 16 + m16][quad * 8];
#pragma unroll
        for (int nt = 0; nt < 8; ++nt) {
            f16x8 bfrag = *(const f16x8*)&Bs[nt * 16 + m16][quad * 8];
            acc[nt] = __builtin_amdgcn_mfma_f32_16x16x32_f16(afrag, bfrag, acc[nt], 0, 0, 0);
        }
    }
    // ---- epilogue: C/D layout col=lane&15, row=quad*4+r
#pragma unroll
    for (int nt = 0; nt < 8; ++nt)
#pragma unroll
        for (int r = 0; r < 4; ++r) {
            int gm = blockRow + wave * 16 + quad * 4 + r;
            int gn = nt * 16 + m16;
            if (gm < N) H[(size_t)gm * 128 + gn] = (_Float16)acc[nt][r];
        }
}

// ---------------------------------------------------------------- Fused agg1 + gemm2
// One wave per node; lane l owns feats [2l, 2l+1]; depth-4 double-buffered
// prefetch (proven best). Two half-range launches for profiler visibility.
__global__ __launch_bounds__(256) void agg1_gemm2(const _Float16* __restrict__ H,
                                                  const int* __restrict__ cnt,
                                                  const int* __restrict__ col,
                                                  const float* __restrict__ b1,
                                                  const float* __restrict__ W2,
                                                  float* __restrict__ Z,
                                                  int nbase, int ncount) {
    const int nr   = (blockIdx.x * blockDim.x + threadIdx.x) >> 6;
    const int lane = threadIdx.x & 63;
    if (nr >= ncount) return;
    const int n = nbase + nr;
    const int c = min(cnt[n], CAP);

    int sv = n;
    if (lane < c) sv = col[n * CAP + lane];
    const float dvw = rsqrtf((float)cnt[sv] + 1.0f);
    const float dv  = (lane <= c) ? dvw : 0.0f;

    const _Float16* hbase = H + lane * 2;
    const int ned4 = (c + 1 + 3) & ~3;

    f16x2 va[4]; float wa[4];
#pragma unroll
    for (int t = 0; t < 4; ++t) {
        const int   e = min(t, 63);
        const int   s = __shfl(sv, e);
        wa[t]         = __shfl(dv, e);
        va[t] = *(const f16x2*)&hbase[(size_t)s * 128];
    }
    float ax = 0.f, ay = 0.f;
    for (int j = 4; j < ned4; j += 4) {
        f16x2 vb[4]; float wb[4];
#pragma unroll
        for (int t = 0; t < 4; ++t) {
            const int   e = min(j + t, 63);
            const int   s = __shfl(sv, e);
            wb[t]         = __shfl(dv, e);
            vb[t] = *(const f16x2*)&hbase[(size_t)s * 128];
        }
#pragma unroll
        for (int t = 0; t < 4; ++t) {
            ax = fmaf(wa[t], (float)va[t][0], ax);
            ay = fmaf(wa[t], (float)va[t][1], ay);
            va[t] = vb[t]; wa[t] = wb[t];
        }
    }
#pragma unroll
    for (int t = 0; t < 4; ++t) {
        ax = fmaf(wa[t], (float)va[t][0], ax);
        ay = fmaf(wa[t], (float)va[t][1], ay);
    }

    const float dn = __shfl(dv, c);         // dinv[n]
    const float2 b = *(const float2*)&b1[lane * 2];
    const float hr0 = fmaxf(ax * dn + b.x, 0.f);
    const float hr1 = fmaxf(ay * dn + b.y, 0.f);

    const float4 wa0 = *(const float4*)&W2[(size_t)(lane * 2) * 8];
    const float4 wa1 = *(const float4*)&W2[(size_t)(lane * 2) * 8 + 4];
    const float4 wb0 = *(const float4*)&W2[(size_t)(lane * 2 + 1) * 8];
    const float4 wb1 = *(const float4*)&W2[(size_t)(lane * 2 + 1) * 8 + 4];
    float p[8];
    p[0] = hr0 * wa0.x + hr1 * wb0.x;
    p[1] = hr0 * wa0.y + hr1 * wb0.y;
    p[2] = hr0 * wa0.z + hr1 * wb0.z;
    p[3] = hr0 * wa0.w + hr1 * wb0.w;
    p[4] = hr0 * wa1.x + hr1 * wb1.x;
    p[5] = hr0 * wa1.y + hr1 * wb1.y;
    p[6] = hr0 * wa1.z + hr1 * wb1.z;
    p[7] = hr0 * wa1.w + hr1 * wb1.w;
#pragma unroll
    for (int off = 32; off > 0; off >>= 1)
#pragma unroll
        for (int j = 0; j < 8; ++j) p[j] += __shfl_xor(p[j], off);
    if (lane == 0) {
        *(float4*)&Z[(size_t)n * 8]     = make_float4(p[0], p[1], p[2], p[3]);
        *(float4*)&Z[(size_t)n * 8 + 4] = make_float4(p[4], p[5], p[6], p[7]);
    }
}

// ---------------------------------------------------------------- Aggregation layer 2 (F=8)
// Thread per node, depth-4 prefetch; 64-thread blocks for CU load-balance.
__global__ __launch_bounds__(64) void agg2(const float* __restrict__ Z,
                                           const int* __restrict__ cnt,
                                           const int* __restrict__ col,
                                           const float* __restrict__ b2,
                                           float* __restrict__ ZA) {
    const int n = blockIdx.x * blockDim.x + threadIdx.x;
    if (n >= N) return;
    const int c = min(cnt[n], CAP);
    float acc[8] = {};

    float4 va0[4], va1[4]; float wv[4];
#pragma unroll
    for (int t = 0; t < 4; ++t) {
        const int s = (t < c) ? col[n * CAP + t] : n;
        wv[t]  = (t < c) ? rsqrtf((float)cnt[s] + 1.0f) : 0.0f;
        va0[t] = *(const float4*)&Z[(size_t)s * 8];
        va1[t] = *(const float4*)&Z[(size_t)s * 8 + 4];
    }
    for (int j = 4; j + 4 <= c + 4; j += 4) {
        float4 vb0[4], vb1[4]; float wb[4];
#pragma unroll
        for (int t = 0; t < 4; ++t) {
            const int jt = j + t;
            const int s  = (jt < c) ? col[n * CAP + jt] : n;
            wb[t]  = (jt < c) ? rsqrtf((float)cnt[s] + 1.0f) : 0.0f;
            vb0[t] = *(const float4*)&Z[(size_t)s * 8];
            vb1[t] = *(const float4*)&Z[(size_t)s * 8 + 4];
        }
#pragma unroll
        for (int t = 0; t < 4; ++t) {
            const float w = wv[t];
            acc[0] = fmaf(w, va0[t].x, acc[0]); acc[1] = fmaf(w, va0[t].y, acc[1]);
            acc[2] = fmaf(w, va0[t].z, acc[2]); acc[3] = fmaf(w, va0[t].w, acc[3]);
            acc[4] = fmaf(w, va1[t].x, acc[4]); acc[5] = fmaf(w, va1[t].y, acc[5]);
            acc[6] = fmaf(w, va1[t].z, acc[6]); acc[7] = fmaf(w, va1[t].w, acc[7]);
            va0[t] = vb0[t]; va1[t] = vb1[t]; wv[t] = wb[t];
        }
    }
#pragma unroll
    for (int t = 0; t < 4; ++t) {
        const float w = wv[t];
        acc[0] = fmaf(w, va0[t].x, acc[0]); acc[1] = fmaf(w, va0[t].y, acc[1]);
        acc[2] = fmaf(w, va0[t].z, acc[2]); acc[3] = fmaf(w, va0[t].w, acc[3]);
        acc[4] = fmaf(w, va1[t].x, acc[4]); acc[5] = fmaf(w, va1[t].y, acc[5]);
        acc[6] = fmaf(w, va1[t].z, acc[6]); acc[7] = fmaf(w, va1[t].w, acc[7]);
    }

    const float dn = rsqrtf((float)c + 1.0f);
    const float4 zn0 = *(const float4*)&Z[(size_t)n * 8];
    const float4 zn1 = *(const float4*)&Z[(size_t)n * 8 + 4];
    float o[8];
    o[0] = (acc[0] + dn * zn0.x) * dn + b2[0];
    o[1] = (acc[1] + dn * zn0.y) * dn + b2[1];
    o[2] = (acc[2] + dn * zn0.z) * dn + b2[2];
    o[3] = (acc[3] + dn * zn0.w) * dn + b2[3];
    o[4] = (acc[4] + dn * zn1.x) * dn + b2[4];
    o[5] = (acc[5] + dn * zn1.y) * dn + b2[5];
    o[6] = (acc[6] + dn * zn1.z) * dn + b2[6];
    o[7] = (acc[7] + dn * zn1.w) * dn + b2[7];
    *(float4*)&ZA[(size_t)n * 8]     = make_float4(o[0], o[1], o[2], o[3]);
    *(float4*)&ZA[(size_t)n * 8 + 4] = make_float4(o[4], o[5], o[6], o[7]);
}

// ---------------------------------------------------------------- Edge scoring
__global__ __launch_bounds__(256) void score(const float* __restrict__ ZA,
                                             const int* __restrict__ pe,
                                             const int* __restrict__ ne,
                                             float* __restrict__ out) {
    const int e = blockIdx.x * blockDim.x + threadIdx.x;
    if (e >= ES) return;
    int a, b;
    if (e < EP) { a = pe[e];      b = pe[EP + e]; }
    else        { a = ne[e - EP]; b = ne[e];      }
    const float4 xa0 = *(const float4*)&ZA[(size_t)a * 8];
    const float4 xa1 = *(const float4*)&ZA[(size_t)a * 8 + 4];
    const float4 xb0 = *(const float4*)&ZA[(size_t)b * 8];
    const float4 xb1 = *(const float4*)&ZA[(size_t)b * 8 + 4];
    out[e] = xa0.x * xb0.x + xa0.y * xb0.y + xa0.z * xb0.z + xa0.w * xb0.w +
             xa1.x * xb1.x + xa1.y * xb1.y + xa1.z * xb1.z + xa1.w * xb1.w;
}

// ---------------------------------------------------------------- launch

extern "C" void kernel_launch(void* const* d_in, const int* in_sizes, int n_in,
                              void* d_out, int out_size, void* d_ws, size_t ws_size,
                              hipStream_t stream) {
    const float* x  = (const float*)d_in[0];
    const int*   ei = (const int*)d_in[1];   // [2, 1.6M] row-major
    const int*   pe = (const int*)d_in[2];   // [2, 200k]
    const int*   ne = (const int*)d_in[3];   // [2, 200k]
    const float* W1 = (const float*)d_in[4];
    const float* b1 = (const float*)d_in[5];
    const float* W2 = (const float*)d_in[6];
    const float* b2 = (const float*)d_in[7];
    float* out = (float*)d_out;

    char* ws = (char*)d_ws;
    size_t off = 0;
    auto carve = [&](size_t bytes) {
        char* p = ws + off;
        off += (bytes + 255) & ~(size_t)255;
        return p;
    };
    int*       cnt = (int*)      carve((size_t)N * sizeof(int));            // 0.4 MB
    int*       col = (int*)      carve((size_t)N * CAP * sizeof(int));      // 25.6 MB
    _Float16*  H   = (_Float16*) carve((size_t)N * 128 * sizeof(_Float16)); // 25.6 MB
    float*     Z   = (float*)    carve((size_t)N * 8 * sizeof(float));      // 3.2 MB
    float*     ZA  = (float*)    carve((size_t)N * 8 * sizeof(float));      // 3.2 MB

    hipMemsetAsync(cnt, 0, (size_t)N * sizeof(int), stream);
    fill_buckets<<<XG * (E / 256), 256, 0, stream>>>(ei, cnt, col);
    gemm1_mfma  <<<(N + 63) / 64, 256, 0, stream>>>(x, W1, H);
    agg1_gemm2  <<<(NH * 64 + 255) / 256, 256, 0, stream>>>(H, cnt, col, b1, W2, Z, 0, NH);
    agg1_gemm2  <<<((N - NH) * 64 + 255) / 256, 256, 0, stream>>>(H, cnt, col, b1, W2, Z, NH, N - NH);
    agg2        <<<(N + 63) / 64, 64, 0, stream>>>(Z, cnt, col, b2, ZA);
    score       <<<(ES + 255) / 256, 256, 0, stream>>>(ZA, pe, ne, out);
}